// Round 2
// baseline (258.131 us; speedup 1.0000x reference)
//
#include <hip/hip_runtime.h>
#include <cstdint>
#include <cstddef>

#define B    8
#define SEQ  2048
#define H    4
#define DKN  5
#define DIM  20
#define PRE8 8
#define SENTB ((short)0xC2FC) // bf16(-126): sentinel bias product -> t=122 -> P bits ~ 0
#define ONEB  ((short)0x3F80) // bf16(1.0)
#define B128  ((short)0x4300) // bf16(128.0) - Q bias slot (x128 folded into scores)
// MAGIC (2^23 sticky-int) + Schraudolph bias (127*128 - minimax shift).
// D = MAGIC + 128*score + 16250 stays in [2^23,2^24): low16 bits of D ARE bf16(2^score).
#define PBIASM 12599162.0f

typedef short short8 __attribute__((ext_vector_type(8)));
typedef float f32x16 __attribute__((ext_vector_type(16)));

static __device__ __forceinline__ unsigned short bf16b(float x) {
    union { float f; unsigned u; } v; v.f = x;
    unsigned r = v.u + 0x7FFFu + ((v.u >> 16) & 1u);   // RTNE
    return (unsigned short)(r >> 16);
}
static __device__ __forceinline__ float bf16f(unsigned short h) {
    union { unsigned u; float f; } v; v.u = ((unsigned)h) << 16;
    return v.f;
}
// P-gen = ONE v_perm per pair: D-reg low16 bits are already the bf16 P value.
static __device__ __forceinline__ unsigned pk_pbits(float ta, float tb) {
    unsigned ia, ib;
    __builtin_memcpy(&ia, &ta, 4);
    __builtin_memcpy(&ib, &tb, 4);
    return __builtin_amdgcn_perm(ib, ia, 0x05040100u);  // {lo16(ib), lo16(ia)}
}
// key offset t (0..31) -> Vt physical column slot (32x32x16 PV k-slot inverse)
static __device__ __forceinline__ int sig32(int t) {
    return (t & 19) | ((t & 4) << 1) | ((t & 8) >> 1);
}

// ws layout:
//   Qt : short [x][b][h][s][16]   hi(0..7, [5]=128 bias) | lo(8..15, [5]=0)  6 MB
//   Kt : short [x][b][h][c][8]    compacted keys; c>=cnt sentinel            3 MB
//   Vt : short [x][b][h][c/32][8][32]  BLOCKED transposed values: per 32-key
//        tile, 8 rows x 32 sig32-permuted cols contiguous (512 B)            3 MB
//   pre : float [p][b][h][s][8]                                             12.6 MB
//   meta: int [B]

// ---------------- projections + in-block windowed compaction ----------------
__global__ __launch_bounds__(256) void proj_kernel(
    const float* __restrict__ q, const float* __restrict__ k, const float* __restrict__ v,
    const float* __restrict__ W0, const float* __restrict__ b0,
    const float* __restrict__ W1, const float* __restrict__ b1,
    const float* __restrict__ W2, const float* __restrict__ b2,
    const int* __restrict__ mask,
    short* __restrict__ Qt, short* __restrict__ Kt, short* __restrict__ Vt,
    int* __restrict__ meta)
{
    __shared__ float Ws[3][DIM * DIM];
    __shared__ float bsh[3][DIM];
    __shared__ int   widx[256];
    __shared__ int   cntS;

    int tid = threadIdx.x;
    int blk = blockIdx.x;            // 3*8*4*8 = 768
    int w   = blk & 7;  blk >>= 3;   // s-window
    int h   = blk & 3;  blk >>= 2;
    int bb  = blk & 7;  blk >>= 3;
    int x   = blk;                   // 0..2
    int s0  = w * 256;

    for (int i = tid; i < DIM * DIM; i += 256) {
        Ws[0][i] = W0[i]; Ws[1][i] = W1[i]; Ws[2][i] = W2[i];
    }
    if (tid < DIM) { bsh[0][tid] = b0[tid]; bsh[1][tid] = b1[tid]; bsh[2][tid] = b2[tid]; }

    // wave 0: scan mask[bb], record gather indices for compacted window [s0,s0+256)
    if (tid < 64) {
        const int* mrow = mask + bb * SEQ;
        int base = 0;
        for (int ch = 0; ch < SEQ; ch += 64) {
            int mv = mrow[ch + tid];
            unsigned long long bal = __ballot(mv != 0);
            int pos = base + (int)__popcll(bal & ((1ull << tid) - 1ull));
            if (mv && pos >= s0 && pos < s0 + 256) widx[pos - s0] = ch + tid;
            base += (int)__popcll(bal);
        }
        if (tid == 0) {
            cntS = base;
            if (x == 0 && h == 0 && w == 0) meta[bb] = base;
        }
    }
    __syncthreads();

    int  cnt   = cntS;
    int  c     = s0 + tid;
    bool valid = c < cnt;
    int  gs    = valid ? widx[tid] : 0;

    // (1/sqrt5)*log2(e)*128 — x128 makes the MFMA emit Schraudolph's 128*x directly
    const float QSC = 0.44721359549995793f * 1.4426950408889634f * 128.0f;
    const float* base = (x == 0) ? q : ((x == 1) ? k : v);

    float xq[DIM], xg[DIM];
    {
        const float4* r4 = (const float4*)(base + (size_t)(bb * SEQ + c) * DIM);
        const float4* g4 = (const float4*)(base + (size_t)(bb * SEQ + gs) * DIM);
        #pragma unroll
        for (int i = 0; i < 5; ++i) {
            float4 a = r4[i], g = g4[i];
            xq[i*4+0]=a.x; xq[i*4+1]=a.y; xq[i*4+2]=a.z; xq[i*4+3]=a.w;
            xg[i*4+0]=g.x; xg[i*4+1]=g.y; xg[i*4+2]=g.z; xg[i*4+3]=g.w;
        }
    }

    #define DOT20(xv, t, j, dst) {                                        \
        float acc_ = bsh[t][j];                                           \
        const float4* wr_ = (const float4*)&Ws[t][(j) * DIM];             \
        _Pragma("unroll")                                                 \
        for (int i4 = 0; i4 < 5; ++i4) {                                  \
            float4 w_ = wr_[i4];                                          \
            acc_ += (xv)[i4*4+0]*w_.x + (xv)[i4*4+1]*w_.y                 \
                  + (xv)[i4*4+2]*w_.z + (xv)[i4*4+3]*w_.w;                \
        }                                                                 \
        dst = acc_;                                                       \
    }

    size_t row = ((size_t)(x * B + bb) * H + h) * SEQ + c;

    // Q-role (W0): pre-scaled (incl. x128), hi/lo bf16 split; hi[5]=128 (bias), lo[5]=0
    short8 qhi = {0, 0, 0, 0, 0, B128, 0, 0};
    short8 qlo = {0, 0, 0, 0, 0, 0, 0, 0};
    #pragma unroll
    for (int d = 0; d < DKN; ++d) {
        float y; DOT20(xq, 0, h * DKN + d, y);
        y *= QSC;
        unsigned short hb = bf16b(y);
        qhi[d] = (short)hb;
        qlo[d] = (short)bf16b(y - bf16f(hb));
    }
    ((short8*)Qt)[row * 2 + 0] = qhi;
    ((short8*)Qt)[row * 2 + 1] = qlo;

    // K-role (W1) on gathered key row, or sentinel:
    // sentinel K = [0,0,0,0,0,-126,0,0] -> t = 16250 - 126*128 = 122 -> P bits ~ 0
    short8 rk = {0, 0, 0, 0, 0, valid ? (short)0 : SENTB, 0, 0};
    if (valid) {
        #pragma unroll
        for (int d = 0; d < DKN; ++d) {
            float y; DOT20(xg, 1, h * DKN + d, y);
            rk[d] = (short)bf16b(y);
        }
    }
    ((short8*)Kt)[row] = rk;

    // V-role (W2): BLOCKED transposed store — tile (c>>5), row d, col sig32(c&31).
    if (valid) {
        size_t vb = ((size_t)(x * B + bb) * H + h) * 8 * SEQ;
        size_t vcell = vb + (size_t)(c >> 5) * 256 + sig32(c & 31);
        #pragma unroll
        for (int d = 0; d < DKN; ++d) {
            float y; DOT20(xg, 2, h * DKN + d, y);
            Vt[vcell + (size_t)d * 32] = (short)bf16b(y);
        }
        Vt[vcell + (size_t)5 * 32] = ONEB;
    }
}

// ---------------- barrier-free MFMA flash attention (32x32x16 S^T form) ----------------
// R20: break the accumulator dependency chain.
//   R1 post-mortem: occupancy/locality were not binding — per-wave iteration wall
//   (~1100 cyc) >> MFMA issue (384 cyc) because acc[t] took 4 serially dependent
//   PV MFMAs per iter (vaA->vcA->vaB->vcB, ~100cy latency each) fed by QK->perm.
//   Fix: (a) dual accumulators accA/accB per q-tile (A-blocks vs B-blocks, summed
//   in epilogue) -> 4 independent 2-deep PV chains per wave; (b) all 4 QK MFMAs
//   issued up front (independent of PV); (c) setprio dropped — the intrinsic is a
//   scheduling fence that blocked A/B-half interleave.
// XCD-affine swizzle preserved: blockIdx = qtq*192 + group(p,b,h); blocks sharing
// a K/V stream differ by 192 = 0 (mod 8) -> same XCD under round-robin dispatch.
__global__ __launch_bounds__(128, 4) void attn_kernel(
    const short* __restrict__ Qt, const short* __restrict__ Kt,
    const short* __restrict__ Vt, const int* __restrict__ meta,
    float* __restrict__ pre)
{
    int lane = threadIdx.x & 63;
    int l31  = lane & 31, half = lane >> 5;

    int wid  = blockIdx.x;            // 3072 = 16 qtq * 192 group
    int qtq  = wid / 192;             // 0..15
    int grp  = wid - qtq * 192;       // (p,b,h)
    int h    = grp & 3;  grp >>= 2;
    int b    = grp & 7;  grp >>= 3;
    int p    = grp;                   // 0..5
    int a    = (0x212010 >> (4 * p)) & 0xF;   // Q source
    int kv   = (0x120201 >> (4 * p)) & 0xF;   // K/V source
    int qt0  = qtq * 4 + (threadIdx.x >> 6) * 2;   // first of this wave's 2 q-tiles

    int cnt  = meta[b];
    int kend = (cnt + 63) & ~63;             // 64-aligned; sentinel K rows pad

    const short*  Qb = Qt + ((size_t)(a  * B + b) * H + h) * SEQ * 16;
    const short8* Kb = (const short8*)Kt + ((size_t)(kv * B + b) * H + h) * SEQ;
    const short*  Vb = Vt + ((size_t)(kv * B + b) * H + h) * 8 * SEQ;
    // blocked layout: row (l31&7) stride 32 shorts, tile stride 256 shorts (= c*8)
    const short*  Vr = Vb + (size_t)(l31 & 7) * 32 + half * 8;

    // B-frag Q: B[n=q=l31][k=half*8+j]; half0 = Q-hi (k0-7), half1 = Q-lo (k8-15)
    short8 qf0, qf1;
    f32x16 zc = {0.f,0.f,0.f,0.f,0.f,0.f,0.f,0.f,0.f,0.f,0.f,0.f,0.f,0.f,0.f,0.f};
    f32x16 sb = {PBIASM,PBIASM,PBIASM,PBIASM,PBIASM,PBIASM,PBIASM,PBIASM,
                 PBIASM,PBIASM,PBIASM,PBIASM,PBIASM,PBIASM,PBIASM,PBIASM};
    qf0 = *(const short8*)(Qb + (size_t)((qt0 + 0) * 32 + l31) * 16 + half * 8);
    qf1 = *(const short8*)(Qb + (size_t)((qt0 + 1) * 32 + l31) * 16 + half * 8);
    f32x16 accA0 = zc, accB0 = zc, accA1 = zc, accB1 = zc;

    // prefetch iteration 0 (64 keys: sub-steps A and B; V tiles at c*8)
    short8 kfA = Kb[l31],      kfB = Kb[32 + l31];
    short8 vaA = *(const short8*)(Vr);
    short8 vcA = *(const short8*)(Vr + 16);
    short8 vaB = *(const short8*)(Vr + 256);
    short8 vcB = *(const short8*)(Vr + 272);

    // p-gen + PV pair into a dedicated accumulator (2-deep chain per acc per iter)
    #define PVSTEP(D, VA, VC, ACC) {                                          \
        unsigned p0_[4], p1_[4];                                              \
        _Pragma("unroll")                                                     \
        for (int r = 0; r < 4; ++r) {                                         \
            p0_[r] = pk_pbits(D[2 * r],     D[2 * r + 1]);                    \
            p1_[r] = pk_pbits(D[2 * r + 8], D[2 * r + 9]);                    \
        }                                                                     \
        short8 f0_, f1_;                                                      \
        __builtin_memcpy(&f0_, p0_, 16);                                      \
        __builtin_memcpy(&f1_, p1_, 16);                                      \
        ACC = __builtin_amdgcn_mfma_f32_32x32x16_bf16(VA, f0_, ACC, 0, 0, 0); \
        ACC = __builtin_amdgcn_mfma_f32_32x32x16_bf16(VC, f1_, ACC, 0, 0, 0); \
    }

    for (int c0 = 0; c0 < kend; c0 += 64) {
        int c1 = c0 + 64;   // final prefetch reads stray in-ws bytes, never consumed
        const short* Vn = Vr + (size_t)c1 * 8;

        // next-iter loads issued first: a full iteration of compute to hide under
        short8 kfA_n = Kb[c1 + l31];
        short8 kfB_n = Kb[c1 + 32 + l31];
        short8 vaA_n = *(const short8*)(Vn);
        short8 vcA_n = *(const short8*)(Vn + 16);
        short8 vaB_n = *(const short8*)(Vn + 256);
        short8 vcB_n = *(const short8*)(Vn + 272);

        // 4 independent QK MFMAs up front: S^T + magic
        // D = MAGIC + 128*score + bias; col=q, key=(reg&3)+8*(reg>>2)+4*half
        f32x16 d0A = __builtin_amdgcn_mfma_f32_32x32x16_bf16(kfA, qf0, sb, 0, 0, 0);
        f32x16 d0B = __builtin_amdgcn_mfma_f32_32x32x16_bf16(kfB, qf0, sb, 0, 0, 0);
        f32x16 d1A = __builtin_amdgcn_mfma_f32_32x32x16_bf16(kfA, qf1, sb, 0, 0, 0);
        f32x16 d1B = __builtin_amdgcn_mfma_f32_32x32x16_bf16(kfB, qf1, sb, 0, 0, 0);

        // 4 independent p-gen + PV chains (2-deep each)
        PVSTEP(d0A, vaA, vcA, accA0);
        PVSTEP(d0B, vaB, vcB, accB0);
        PVSTEP(d1A, vaA, vcA, accA1);
        PVSTEP(d1B, vaB, vcB, accB1);

        kfA = kfA_n; kfB = kfB_n;
        vaA = vaA_n; vcA = vcA_n; vaB = vaB_n; vcB = vcB_n;
    }

    // D rows: dim0-3 = half0 regs 0-3; dim4 = half1 reg0; l (row5) = half1 reg1
    float* base0 = pre + (((size_t)p * B + b) * H + h) * SEQ * PRE8;
    #pragma unroll
    for (int t = 0; t < 2; ++t) {
        f32x16 accS;
        if (t == 0) { accS = accA0 + accB0; } else { accS = accA1 + accB1; }
        int qb = (qt0 + t) * 32;
        float lv  = __shfl(accS[1], 32 + l31, 64);
        float inv = 1.0f / lv;
        float* dst = base0 + (size_t)(qb + l31) * PRE8;
        if (half == 0)
            *(float4*)dst = make_float4(accS[0]*inv, accS[1]*inv,
                                        accS[2]*inv, accS[3]*inv);
        else
            dst[4] = accS[0] * inv;
    }
}

// ---------------- sum 6 pairs + output projection ----------------
__global__ __launch_bounds__(64) void final_kernel(
    const float* __restrict__ pre,
    const float* __restrict__ W3, const float* __restrict__ b3,
    float* __restrict__ out)
{
    __shared__ float Ws[DIM * DIM];
    __shared__ float bs[DIM];
    int tid = threadIdx.x;
    for (int i = tid; i < DIM * DIM; i += 64) Ws[i] = W3[i];
    if (tid < DIM) bs[tid] = b3[tid];
    __syncthreads();

    int g = blockIdx.x * 64 + tid;       // B*SEQ = 16384 exactly
    int b = g / SEQ;
    int s = g - b * SEQ;

    float x[DIM];
    #pragma unroll
    for (int i = 0; i < DIM; ++i) x[i] = 0.f;

    for (int p = 0; p < 6; ++p) {
        #pragma unroll
        for (int h = 0; h < H; ++h) {
            const float* sr = pre + (((size_t)p * B + b) * H + h) * SEQ * PRE8
                                  + (size_t)s * PRE8;
            float4 a = *(const float4*)sr;
            float  a4 = sr[4];
            x[h * DKN + 0] += a.x; x[h * DKN + 1] += a.y; x[h * DKN + 2] += a.z;
            x[h * DKN + 3] += a.w; x[h * DKN + 4] += a4;
        }
    }

    float y[DIM];
    for (int j = 0; j < DIM; ++j) {
        float acc = bs[j];
        const float4* wr = (const float4*)&Ws[j * DIM];
        #pragma unroll
        for (int i4 = 0; i4 < 5; ++i4) {
            float4 w = wr[i4];
            acc += x[i4*4+0]*w.x + x[i4*4+1]*w.y + x[i4*4+2]*w.z + x[i4*4+3]*w.w;
        }
        y[j] = acc;
    }
    float4* dst = (float4*)(out + (size_t)(b * SEQ + s) * DIM);
    #pragma unroll
    for (int j4 = 0; j4 < 5; ++j4)
        dst[j4] = make_float4(y[j4*4+0], y[j4*4+1], y[j4*4+2], y[j4*4+3]);
}

extern "C" void kernel_launch(void* const* d_in, const int* in_sizes, int n_in,
                              void* d_out, int out_size, void* d_ws, size_t ws_size,
                              hipStream_t stream) {
    const float* q    = (const float*)d_in[0];
    const float* k    = (const float*)d_in[1];
    const float* v    = (const float*)d_in[2];
    const int*   mask = (const int*)d_in[3];
    const float* W0 = (const float*)d_in[4];  const float* b0 = (const float*)d_in[5];
    const float* W1 = (const float*)d_in[6];  const float* b1 = (const float*)d_in[7];
    const float* W2 = (const float*)d_in[8];  const float* b2 = (const float*)d_in[9];
    const float* W3 = (const float*)d_in[10]; const float* b3 = (const float*)d_in[11];

    const size_t NROW = (size_t)3 * B * H * SEQ;       // 196608
    short* Qt = (short*)d_ws;                          // NROW*16 shorts (6 MB)
    short* Kt = Qt + NROW * 16;                        // NROW*8 shorts  (3 MB)
    short* Vt = Kt + NROW * 8;                         // NROW*8 shorts  (3 MB)
    float* pre = (float*)(Vt + NROW * 8);              // 6*B*H*SEQ*8 floats (12.6 MB)
    int*   meta = (int*)(pre + (size_t)6 * B * H * SEQ * PRE8);
    float* out = (float*)d_out;

    proj_kernel<<<dim3(3 * B * H * (SEQ / 256)), dim3(256), 0, stream>>>(
        q, k, v, W0, b0, W1, b1, W2, b2, mask, Qt, Kt, Vt, meta);
    attn_kernel<<<dim3(6 * B * H * 16), dim3(128), 0, stream>>>(
        Qt, Kt, Vt, meta, pre);
    final_kernel<<<dim3(B * SEQ / 64), dim3(64), 0, stream>>>(pre, W3, b3, out);
}

// Round 3
// 137.247 us; speedup vs baseline: 1.8808x; 1.8808x over previous
//
#include <hip/hip_runtime.h>
#include <cstdint>
#include <cstddef>

#define B    8
#define SEQ  2048
#define H    4
#define DKN  5
#define DIM  20
#define PRE8 8
#define SENTB ((short)0xC2FC) // bf16(-126): sentinel bias product -> t=122 -> P bits ~ 0
#define ONEB  ((short)0x3F80) // bf16(1.0)
#define B128  ((short)0x4300) // bf16(128.0) - Q bias slot (x128 folded into scores)
// MAGIC (2^23 sticky-int) + Schraudolph bias (127*128 - minimax shift).
// D = MAGIC + 128*score + 16250 stays in [2^23,2^24): low16 bits of D ARE bf16(2^score).
#define PBIASM 12599162.0f

typedef short short8 __attribute__((ext_vector_type(8)));
typedef float f32x16 __attribute__((ext_vector_type(16)));

static __device__ __forceinline__ unsigned short bf16b(float x) {
    union { float f; unsigned u; } v; v.f = x;
    unsigned r = v.u + 0x7FFFu + ((v.u >> 16) & 1u);   // RTNE
    return (unsigned short)(r >> 16);
}
static __device__ __forceinline__ float bf16f(unsigned short h) {
    union { unsigned u; float f; } v; v.u = ((unsigned)h) << 16;
    return v.f;
}
// P-gen = ONE v_perm per pair: D-reg low16 bits are already the bf16 P value.
static __device__ __forceinline__ unsigned pk_pbits(float ta, float tb) {
    unsigned ia, ib;
    __builtin_memcpy(&ia, &ta, 4);
    __builtin_memcpy(&ib, &tb, 4);
    return __builtin_amdgcn_perm(ib, ia, 0x05040100u);  // {lo16(ib), lo16(ia)}
}
// key offset t (0..31) -> Vt physical column slot (32x32x16 PV k-slot inverse)
static __device__ __forceinline__ int sig32(int t) {
    return (t & 19) | ((t & 4) << 1) | ((t & 8) >> 1);
}

// direct global->LDS copy: per-lane 16B from g, lands at (uniform l) + lane*16
typedef unsigned __attribute__((address_space(1))) gas_u32;
typedef unsigned __attribute__((address_space(3))) las_u32;
static __device__ __forceinline__ void glds16(const void* g, void* l) {
    __builtin_amdgcn_global_load_lds((const gas_u32*)g, (las_u32*)l, 16, 0, 0);
}

// ws layout:
//   Qt : short [x][b][h][s][16]   hi(0..7, [5]=128 bias) | lo(8..15, [5]=0)  6 MB
//   Kt : short [x][b][h][c][8]    compacted keys; c>=cnt sentinel            3 MB
//   Vt : short [x][b][h][c/32][8][32]  BLOCKED transposed values: per 32-key
//        tile, 8 rows x 32 sig32-permuted cols contiguous (512 B)            3 MB
//   pre : float [p][b][h][s][8]                                             12.6 MB
//   meta: int [B]

// ---------------- projections + in-block windowed compaction ----------------
__global__ __launch_bounds__(256) void proj_kernel(
    const float* __restrict__ q, const float* __restrict__ k, const float* __restrict__ v,
    const float* __restrict__ W0, const float* __restrict__ b0,
    const float* __restrict__ W1, const float* __restrict__ b1,
    const float* __restrict__ W2, const float* __restrict__ b2,
    const int* __restrict__ mask,
    short* __restrict__ Qt, short* __restrict__ Kt, short* __restrict__ Vt,
    int* __restrict__ meta)
{
    __shared__ float Ws[3][DIM * DIM];
    __shared__ float bsh[3][DIM];
    __shared__ int   widx[256];
    __shared__ int   cntS;

    int tid = threadIdx.x;
    int blk = blockIdx.x;            // 3*8*4*8 = 768
    int w   = blk & 7;  blk >>= 3;   // s-window
    int h   = blk & 3;  blk >>= 2;
    int bb  = blk & 7;  blk >>= 3;
    int x   = blk;                   // 0..2
    int s0  = w * 256;

    for (int i = tid; i < DIM * DIM; i += 256) {
        Ws[0][i] = W0[i]; Ws[1][i] = W1[i]; Ws[2][i] = W2[i];
    }
    if (tid < DIM) { bsh[0][tid] = b0[tid]; bsh[1][tid] = b1[tid]; bsh[2][tid] = b2[tid]; }

    // wave 0: scan mask[bb], record gather indices for compacted window [s0,s0+256)
    if (tid < 64) {
        const int* mrow = mask + bb * SEQ;
        int base = 0;
        for (int ch = 0; ch < SEQ; ch += 64) {
            int mv = mrow[ch + tid];
            unsigned long long bal = __ballot(mv != 0);
            int pos = base + (int)__popcll(bal & ((1ull << tid) - 1ull));
            if (mv && pos >= s0 && pos < s0 + 256) widx[pos - s0] = ch + tid;
            base += (int)__popcll(bal);
        }
        if (tid == 0) {
            cntS = base;
            if (x == 0 && h == 0 && w == 0) meta[bb] = base;
        }
    }
    __syncthreads();

    int  cnt   = cntS;
    int  c     = s0 + tid;
    bool valid = c < cnt;
    int  gs    = valid ? widx[tid] : 0;

    // (1/sqrt5)*log2(e)*128 — x128 makes the MFMA emit Schraudolph's 128*x directly
    const float QSC = 0.44721359549995793f * 1.4426950408889634f * 128.0f;
    const float* base = (x == 0) ? q : ((x == 1) ? k : v);

    float xq[DIM], xg[DIM];
    {
        const float4* r4 = (const float4*)(base + (size_t)(bb * SEQ + c) * DIM);
        const float4* g4 = (const float4*)(base + (size_t)(bb * SEQ + gs) * DIM);
        #pragma unroll
        for (int i = 0; i < 5; ++i) {
            float4 a = r4[i], g = g4[i];
            xq[i*4+0]=a.x; xq[i*4+1]=a.y; xq[i*4+2]=a.z; xq[i*4+3]=a.w;
            xg[i*4+0]=g.x; xg[i*4+1]=g.y; xg[i*4+2]=g.z; xg[i*4+3]=g.w;
        }
    }

    #define DOT20(xv, t, j, dst) {                                        \
        float acc_ = bsh[t][j];                                           \
        const float4* wr_ = (const float4*)&Ws[t][(j) * DIM];             \
        _Pragma("unroll")                                                 \
        for (int i4 = 0; i4 < 5; ++i4) {                                  \
            float4 w_ = wr_[i4];                                          \
            acc_ += (xv)[i4*4+0]*w_.x + (xv)[i4*4+1]*w_.y                 \
                  + (xv)[i4*4+2]*w_.z + (xv)[i4*4+3]*w_.w;                \
        }                                                                 \
        dst = acc_;                                                       \
    }

    size_t row = ((size_t)(x * B + bb) * H + h) * SEQ + c;

    // Q-role (W0): pre-scaled (incl. x128), hi/lo bf16 split; hi[5]=128 (bias), lo[5]=0
    short8 qhi = {0, 0, 0, 0, 0, B128, 0, 0};
    short8 qlo = {0, 0, 0, 0, 0, 0, 0, 0};
    #pragma unroll
    for (int d = 0; d < DKN; ++d) {
        float y; DOT20(xq, 0, h * DKN + d, y);
        y *= QSC;
        unsigned short hb = bf16b(y);
        qhi[d] = (short)hb;
        qlo[d] = (short)bf16b(y - bf16f(hb));
    }
    ((short8*)Qt)[row * 2 + 0] = qhi;
    ((short8*)Qt)[row * 2 + 1] = qlo;

    // K-role (W1) on gathered key row, or sentinel:
    // sentinel K = [0,0,0,0,0,-126,0,0] -> t = 16250 - 126*128 = 122 -> P bits ~ 0
    short8 rk = {0, 0, 0, 0, 0, valid ? (short)0 : SENTB, 0, 0};
    if (valid) {
        #pragma unroll
        for (int d = 0; d < DKN; ++d) {
            float y; DOT20(xg, 1, h * DKN + d, y);
            rk[d] = (short)bf16b(y);
        }
    }
    ((short8*)Kt)[row] = rk;

    // V-role (W2): BLOCKED transposed store — tile (c>>5), row d, col sig32(c&31).
    if (valid) {
        size_t vb = ((size_t)(x * B + bb) * H + h) * 8 * SEQ;
        size_t vcell = vb + (size_t)(c >> 5) * 256 + sig32(c & 31);
        #pragma unroll
        for (int d = 0; d < DKN; ++d) {
            float y; DOT20(xg, 2, h * DKN + d, y);
            Vt[vcell + (size_t)d * 32] = (short)bf16b(y);
        }
        Vt[vcell + (size_t)5 * 32] = ONEB;
    }
}

// ---------------- barrier-free MFMA flash attention (32x32x16 S^T form) ----------------
// R21: LDS-staged K/V via global_load_lds.
//   R1 post-mortem arithmetic: 6 gather loads/wave-iter (V: 16 distinct 16B segs,
//   4-way lane-dup; K: 32 distinct) -> ~100+ TA transactions/wave-iter; at ~8.6
//   waves/CU that saturates the CU address pipe at the observed ~640cy iter wall.
//   Fix: K-tile (1KB) and V-tile (1KB) are CONTIGUOUS in the streams -> 2
//   global_load_lds dwordx4 per iter replace all 6 gathers; fragments come from
//   LDS via 6 ds_read_b128 (separate LGKM pipe, broadcast-friendly).
//   Per-wave private double-buffered LDS slices -> still barrier-free; counted
//   "s_waitcnt vmcnt(2)" (exactly the 2 just-issued glds outstanding) +
//   sched_barrier(0) fences (rule #18: compiler can't see glds->LDS dependency).
//   MFMA DAG and numerics bit-identical to R1 (47.8 us proven).
// XCD-affine swizzle preserved: blockIdx = qtq*192 + group(p,b,h).
__global__ __launch_bounds__(128, 4) void attn_kernel(
    const short* __restrict__ Qt, const short* __restrict__ Kt,
    const short* __restrict__ Vt, const int* __restrict__ meta,
    float* __restrict__ pre)
{
    // [wave][buf][ K 1KB | V 1KB ]
    __shared__ char lds[2][2][2048];

    int wv   = threadIdx.x >> 6;
    int lane = threadIdx.x & 63;
    int l31  = lane & 31, half = lane >> 5;

    int wid  = blockIdx.x;            // 3072 = 16 qtq * 192 group
    int qtq  = wid / 192;             // 0..15
    int grp  = wid - qtq * 192;       // (p,b,h)
    int h    = grp & 3;  grp >>= 2;
    int b    = grp & 7;  grp >>= 3;
    int p    = grp;                   // 0..5
    int a    = (0x212010 >> (4 * p)) & 0xF;   // Q source
    int kv   = (0x120201 >> (4 * p)) & 0xF;   // K/V source
    int qt0  = qtq * 4 + wv * 2;              // first of this wave's 2 q-tiles

    int cnt  = meta[b];
    int kend = (cnt + 63) & ~63;             // 64-aligned; sentinel K rows pad

    const short* Qb  = Qt + ((size_t)(a  * B + b) * H + h) * SEQ * 16;
    const char*  Kst = (const char*)(Kt + ((size_t)(kv * B + b) * H + h) * SEQ * 8);
    const char*  Vst = (const char*)(Vt + ((size_t)(kv * B + b) * H + h) * 8 * SEQ);

    char* myl = &lds[wv][0][0];
    // ds-read byte offsets within a buffer:
    int koff = l31 * 16;                           // kfA; kfB = +512
    int voff = 1024 + (l31 & 7) * 64 + half * 16;  // vaA; vcA +32; vaB +512; vcB +544

    // B-frag Q: B[n=q=l31][k=half*8+j]; half0 = Q-hi (k0-7), half1 = Q-lo (k8-15)
    short8 qf[2];
    f32x16 acc[2];
    f32x16 zc = {0.f,0.f,0.f,0.f,0.f,0.f,0.f,0.f,0.f,0.f,0.f,0.f,0.f,0.f,0.f,0.f};
    f32x16 sb = {PBIASM,PBIASM,PBIASM,PBIASM,PBIASM,PBIASM,PBIASM,PBIASM,
                 PBIASM,PBIASM,PBIASM,PBIASM,PBIASM,PBIASM,PBIASM,PBIASM};
    #pragma unroll
    for (int t = 0; t < 2; ++t) {
        int qb = (qt0 + t) * 32;
        qf[t]  = *(const short8*)(Qb + (size_t)(qb + l31) * 16 + half * 8);
        acc[t] = zc;
    }

    // prologue: stage iteration 0 into buf 0 (K 1KB + V 1KB, contiguous)
    glds16(Kst + lane * 16, myl);
    glds16(Vst + lane * 16, myl + 1024);

    // p-gen + PV pair into acc (same DAG as R1)
    #define PVSTEP(D, VA, VC, ACC) {                                          \
        unsigned p0_[4], p1_[4];                                              \
        _Pragma("unroll")                                                     \
        for (int r = 0; r < 4; ++r) {                                         \
            p0_[r] = pk_pbits(D[2 * r],     D[2 * r + 1]);                    \
            p1_[r] = pk_pbits(D[2 * r + 8], D[2 * r + 9]);                    \
        }                                                                     \
        short8 f0_, f1_;                                                      \
        __builtin_memcpy(&f0_, p0_, 16);                                      \
        __builtin_memcpy(&f1_, p1_, 16);                                      \
        ACC = __builtin_amdgcn_mfma_f32_32x32x16_bf16(VA, f0_, ACC, 0, 0, 0); \
        ACC = __builtin_amdgcn_mfma_f32_32x32x16_bf16(VC, f1_, ACC, 0, 0, 0); \
    }

    int buf = 0;
    for (int c0 = 0; c0 < kend; c0 += 64) {
        size_t c1b = (size_t)(c0 + 64) * 16;   // next tile byte offset in streams
        char* nb = myl + ((buf ^ 1) << 11);
        // stray reads past kend land in adjacent ws regions; never consumed
        glds16(Kst + c1b + lane * 16, nb);
        glds16(Vst + c1b + lane * 16, nb + 1024);

        __builtin_amdgcn_sched_barrier(0);
        asm volatile("s_waitcnt vmcnt(2)" ::: "memory");   // prev pair landed
        __builtin_amdgcn_sched_barrier(0);

        const char* cb = myl + (buf << 11);
        short8 kfA = *(const short8*)(cb + koff);
        short8 vaA = *(const short8*)(cb + voff);
        short8 vcA = *(const short8*)(cb + voff + 32);

        __builtin_amdgcn_s_setprio(1);
        #pragma unroll
        for (int t = 0; t < 2; ++t) {
            // S^T + magic: D = MAGIC + 128*score + bias; col=q, key=(reg&3)+8*(reg>>2)+4*half
            f32x16 dA = __builtin_amdgcn_mfma_f32_32x32x16_bf16(kfA, qf[t], sb, 0, 0, 0);
            PVSTEP(dA, vaA, vcA, acc[t]);
        }
        __builtin_amdgcn_s_setprio(0);

        short8 kfB = *(const short8*)(cb + koff + 512);
        short8 vaB = *(const short8*)(cb + voff + 512);
        short8 vcB = *(const short8*)(cb + voff + 544);

        __builtin_amdgcn_s_setprio(1);
        #pragma unroll
        for (int t = 0; t < 2; ++t) {
            f32x16 dB = __builtin_amdgcn_mfma_f32_32x32x16_bf16(kfB, qf[t], sb, 0, 0, 0);
            PVSTEP(dB, vaB, vcB, acc[t]);
        }
        __builtin_amdgcn_s_setprio(0);

        buf ^= 1;
    }

    // D rows: dim0-3 = half0 regs 0-3; dim4 = half1 reg0; l (row5) = half1 reg1
    float* base0 = pre + (((size_t)p * B + b) * H + h) * SEQ * PRE8;
    #pragma unroll
    for (int t = 0; t < 2; ++t) {
        int qb = (qt0 + t) * 32;
        float lv  = __shfl(acc[t][1], 32 + l31, 64);
        float inv = 1.0f / lv;
        float* dst = base0 + (size_t)(qb + l31) * PRE8;
        if (half == 0)
            *(float4*)dst = make_float4(acc[t][0]*inv, acc[t][1]*inv,
                                        acc[t][2]*inv, acc[t][3]*inv);
        else
            dst[4] = acc[t][0] * inv;
    }
}

// ---------------- sum 6 pairs + output projection ----------------
__global__ __launch_bounds__(64) void final_kernel(
    const float* __restrict__ pre,
    const float* __restrict__ W3, const float* __restrict__ b3,
    float* __restrict__ out)
{
    __shared__ float Ws[DIM * DIM];
    __shared__ float bs[DIM];
    int tid = threadIdx.x;
    for (int i = tid; i < DIM * DIM; i += 64) Ws[i] = W3[i];
    if (tid < DIM) bs[tid] = b3[tid];
    __syncthreads();

    int g = blockIdx.x * 64 + tid;       // B*SEQ = 16384 exactly
    int b = g / SEQ;
    int s = g - b * SEQ;

    float x[DIM];
    #pragma unroll
    for (int i = 0; i < DIM; ++i) x[i] = 0.f;

    for (int p = 0; p < 6; ++p) {
        #pragma unroll
        for (int h = 0; h < H; ++h) {
            const float* sr = pre + (((size_t)p * B + b) * H + h) * SEQ * PRE8
                                  + (size_t)s * PRE8;
            float4 a = *(const float4*)sr;
            float  a4 = sr[4];
            x[h * DKN + 0] += a.x; x[h * DKN + 1] += a.y; x[h * DKN + 2] += a.z;
            x[h * DKN + 3] += a.w; x[h * DKN + 4] += a4;
        }
    }

    float y[DIM];
    for (int j = 0; j < DIM; ++j) {
        float acc = bs[j];
        const float4* wr = (const float4*)&Ws[j * DIM];
        #pragma unroll
        for (int i4 = 0; i4 < 5; ++i4) {
            float4 w = wr[i4];
            acc += x[i4*4+0]*w.x + x[i4*4+1]*w.y + x[i4*4+2]*w.z + x[i4*4+3]*w.w;
        }
        y[j] = acc;
    }
    float4* dst = (float4*)(out + (size_t)(b * SEQ + s) * DIM);
    #pragma unroll
    for (int j4 = 0; j4 < 5; ++j4)
        dst[j4] = make_float4(y[j4*4+0], y[j4*4+1], y[j4*4+2], y[j4*4+3]);
}

extern "C" void kernel_launch(void* const* d_in, const int* in_sizes, int n_in,
                              void* d_out, int out_size, void* d_ws, size_t ws_size,
                              hipStream_t stream) {
    const float* q    = (const float*)d_in[0];
    const float* k    = (const float*)d_in[1];
    const float* v    = (const float*)d_in[2];
    const int*   mask = (const int*)d_in[3];
    const float* W0 = (const float*)d_in[4];  const float* b0 = (const float*)d_in[5];
    const float* W1 = (const float*)d_in[6];  const float* b1 = (const float*)d_in[7];
    const float* W2 = (const float*)d_in[8];  const float* b2 = (const float*)d_in[9];
    const float* W3 = (const float*)d_in[10]; const float* b3 = (const float*)d_in[11];

    const size_t NROW = (size_t)3 * B * H * SEQ;       // 196608
    short* Qt = (short*)d_ws;                          // NROW*16 shorts (6 MB)
    short* Kt = Qt + NROW * 16;                        // NROW*8 shorts  (3 MB)
    short* Vt = Kt + NROW * 8;                         // NROW*8 shorts  (3 MB)
    float* pre = (float*)(Vt + NROW * 8);              // 6*B*H*SEQ*8 floats (12.6 MB)
    int*   meta = (int*)(pre + (size_t)6 * B * H * SEQ * PRE8);
    float* out = (float*)d_out;

    proj_kernel<<<dim3(3 * B * H * (SEQ / 256)), dim3(256), 0, stream>>>(
        q, k, v, W0, b0, W1, b1, W2, b2, mask, Qt, Kt, Vt, meta);
    attn_kernel<<<dim3(6 * B * H * 16), dim3(128), 0, stream>>>(
        Qt, Kt, Vt, meta, pre);
    final_kernel<<<dim3(B * SEQ / 64), dim3(64), 0, stream>>>(pre, W3, b3, out);
}